// Round 4
// baseline (107.683 us; speedup 1.0000x reference)
//
#include <hip/hip_runtime.h>
#include <math.h>

// Capsule conv + dynamic routing via fp16 MFMA (16x16x32), swapped operands:
// A = prepped fp16 weights (M = f), B = LDS input patch (N = px).
// R15: c-PAIR waves. R13 (halved A-traffic) and R14 (LDS A-ring, counted
// vmcnt) were both neutral -> the A-stream is NOT the bottleneck. Audit says
// the LDS pipe is: B-fragments (ds_read_b128, ~12cy) were read redundantly by
// all 8 c-waves (640 KB/block vs 26 KB of patch), plus only 2 barrier domains
// per CU. Now each wave owns TWO c's sharing ONE B-read per step
// (1 ds_read + 2 global A + 2 MFMA). Block = 256 thr / 4 waves / 16 px,
// grid = 2048, LDS 24.4 KB -> 4 resident blocks/CU (4 barrier domains).
// B LDS traffic per px halves; A L2 traffic doubles (proven non-binding).
// acc = 2c x 8i x f32x4 = 64 regs, same 128-reg budget as proven R12.
// NOTE: hipLaunchCooperativeKernel is NOT graph-capturable here (R7 failed);
// ~44us d_ws re-poison fill + ~12us restore/launch are fixed harness overhead.
//
// x:    [B=32][H=32][W=32][128] fp32 (128 = i*16+cin)
// wts:  [i=8][k=144][o=128] fp32 -> w16[(i*5+q)][c][lane][j]
//       = wts[(i*144 + q*32 + (lane>>4)*8 + j)*128 + c*16 + (lane&15)], 0 for k>=144
// out:  [B][H][W][128] fp32 (o = c*16+f)
//
// Block = 256 = 4 waves; wave w = c-pair {2w, 2w+1}; 16 px (half row).
// Grid = 2048: bid -> half = bid&1, h = (bid>>1)&31, b = bid>>6.
// MFMA 16x16x32: A[m=lane&15 -> f][k=quad*8+j], B[k][n=lane&15 -> px].
// D: px = half*16 + lane&15, f = quad*4 + reg.

typedef _Float16 fp16x8 __attribute__((ext_vector_type(8)));
typedef float f32x4 __attribute__((ext_vector_type(4)));

#define EPS 1e-7f
constexpr int PSTRIDE = 136;   // fp16 elems; 272B row stride: 16B-aligned, 2-way banks (free)
constexpr int PCOLS   = 18;    // 16 px + 2 halo
constexpr int LSTRIDE = 76;    // lg_arr: [px*76 + i*9 + c]
constexpr int PXS     = 76;    // r_arr:  [px*76 + c*8 + i]; b128 stride 304B -> 2-way (free)
constexpr int W_ELEMS = 40 * 8 * 64 * 8;   // 163840

// sum across the 4 quads (lanes ^16, ^32); all lanes receive the total
__device__ __forceinline__ float sumquad(float v) {
    v += __shfl_xor(v, 16);
    v += __shfl_xor(v, 32);
    return v;
}

// prep: direct scatter, 640 blocks x 256 threads, 1 element each (R8-proven).
__global__ __launch_bounds__(256)
void prep_weights(const float* __restrict__ wts,
                  _Float16* __restrict__ w16) {
    int n = blockIdx.x * 256 + threadIdx.x;        // 0..163839
    if (n >= W_ELEMS) return;
    int j    = n & 7;
    int ln   = (n >> 3) & 63;
    int c0   = (n >> 9) & 7;
    int iq   = n >> 12;                            // i*5+q
    int i0   = iq / 5;
    int q0   = iq - i0 * 5;
    int k = q0 * 32 + (ln >> 4) * 8 + j;
    float w = 0.f;
    if (k < 144) w = wts[(i0 * 144 + k) * 128 + c0 * 16 + (ln & 15)];
    w16[n] = (_Float16)w;                          // RNE
}

__global__ __launch_bounds__(256, 4)
void capsule_mfma_kernel(const float* __restrict__ x,
                         const _Float16* __restrict__ w16,
                         const float* __restrict__ bias,
                         float* __restrict__ out)
{
    __shared__ _Float16 patch[3 * PCOLS * PSTRIDE];      // 14688 B
    __shared__ float lg_arr[16 * LSTRIDE];               // 4864 B
    __shared__ float r_arr[16 * PXS];                    // 4864 B

    const int tid  = threadIdx.x;
    const int lane = tid & 63;
    const int w    = tid >> 6;     // wave = c-pair
    const int c0   = 2 * w;        // first capsule of the pair
    const int l15  = lane & 15;    // A: f ; B & D: px-in-tile
    const int quad = lane >> 4;
    const int lane8 = lane * 8;

    const int bid  = blockIdx.x;
    const int half = bid & 1;
    const int h    = (bid >> 1) & 31;
    const int b    = bid >> 6;
    const int pxbase = half * 16;

    // ---- stage input patch rows h-1..h+1, cols pxbase-1..pxbase+16, fp16 ----
    const float4* x4 = (const float4*)x;
    for (int idx = tid; idx < 3 * PCOLS * 32; idx += 256) {
        int ch4  = idx & 31;
        int slot = idx >> 5;               // row*18 + colp
        int row  = slot / PCOLS;
        int colp = slot - row * PCOLS;
        int gh = h - 1 + row;
        int gw = pxbase + colp - 1;
        float4 v = {0.f, 0.f, 0.f, 0.f};
        if ((unsigned)gh < 32u && (unsigned)gw < 32u)
            v = x4[(((b * 32 + gh) * 32 + gw) << 5) + ch4];
        _Float16 ph[4];
        ph[0] = (_Float16)v.x; ph[1] = (_Float16)v.y;
        ph[2] = (_Float16)v.z; ph[3] = (_Float16)v.w;
        *(ushort4*)&patch[slot * PSTRIDE + ch4 * 4] = *(const ushort4*)ph;
    }
    __syncthreads();

    // ---- B (patch) per-lane offsets: k = q*32 + quad*8 + j; tap = 2q+(quad>>1) ----
    int a_off[5];
    #pragma unroll
    for (int q = 0; q < 5; ++q) {
        int tap = 2 * q + (quad >> 1);
        if (tap > 8) tap = 8;                 // pad region: A is zero there
        int dy = tap / 3, dx = tap - dy * 3;
        a_off[q] = (dy * PCOLS + l15 + dx) * PSTRIDE + (quad & 1) * 8;
    }

    // ---- conv: 40 steps of (1 B ds_read shared by 2 c's, 2 A loads, 2 MFMA) ----
    f32x4 acc[2][8];
    #pragma unroll
    for (int cc = 0; cc < 2; ++cc)
        #pragma unroll
        for (int i = 0; i < 8; ++i) acc[cc][i] = (f32x4){0.f, 0.f, 0.f, 0.f};

    #pragma unroll
    for (int q = 0; q < 5; ++q) {
        #pragma unroll
        for (int i = 0; i < 8; ++i) {
            int woff = ((i * 5 + q) * 8 + c0) * 512 + lane8;
            fp16x8 a0 = *(const fp16x8*)(w16 + woff);
            fp16x8 a1 = *(const fp16x8*)(w16 + woff + 512);
            fp16x8 bb = *(const fp16x8*)(patch + a_off[q] + i * 16);
            acc[0][i] = __builtin_amdgcn_mfma_f32_16x16x32_f16(a0, bb, acc[0][i], 0, 0, 0);
            acc[1][i] = __builtin_amdgcn_mfma_f32_16x16x32_f16(a1, bb, acc[1][i], 0, 0, 0);
        }
    }

    // ---- dynamic routing: thread owns (px = l15, c in {c0, c0+1}, f = quad*4+0..3) ----
    float barr[2][4];
    #pragma unroll
    for (int cc = 0; cc < 2; ++cc) {
        float4 bb4 = *(const float4*)(bias + (c0 + cc) * 16 + quad * 4);
        barr[cc][0] = bb4.x; barr[cc][1] = bb4.y; barr[cc][2] = bb4.z; barr[cc][3] = bb4.w;
    }

    float actv[2][4];

    // iter 0: route = 1/8 uniform
    #pragma unroll
    for (int cc = 0; cc < 2; ++cc) {
        float pre[4];
        #pragma unroll
        for (int r = 0; r < 4; ++r) {
            float s = acc[cc][0][r] + acc[cc][1][r] + acc[cc][2][r] + acc[cc][3][r]
                    + acc[cc][4][r] + acc[cc][5][r] + acc[cc][6][r] + acc[cc][7][r];
            pre[r] = s * 0.125f + barr[cc][r];
        }
        float s2 = sumquad(pre[0]*pre[0] + pre[1]*pre[1] + pre[2]*pre[2] + pre[3]*pre[3]);
        float scale = s2 * __builtin_amdgcn_rsqf(s2 + EPS) * __builtin_amdgcn_rcpf(1.f + s2);
        #pragma unroll
        for (int r = 0; r < 4; ++r) actv[cc][r] = scale * pre[r];
    }
    #pragma unroll
    for (int cc = 0; cc < 2; ++cc)
        #pragma unroll
        for (int i = 0; i < 8; ++i) {
            float t = acc[cc][i][0]*actv[cc][0] + acc[cc][i][1]*actv[cc][1]
                    + acc[cc][i][2]*actv[cc][2] + acc[cc][i][3]*actv[cc][3];
            t = sumquad(t);
            if (quad == 0) lg_arr[l15 * LSTRIDE + i * 9 + (c0 + cc)] = t;
        }
    __syncthreads();
    if (tid < 128) {   // softmax over c for each (px, i): 16*8 = 128 tasks
        int p = tid >> 3, ii = tid & 7;
        const float* lrow = &lg_arr[p * LSTRIDE + ii * 9];
        float m = lrow[0];
        #pragma unroll
        for (int cc = 1; cc < 8; ++cc) m = fmaxf(m, lrow[cc]);
        float e[8]; float den = 0.f;
        #pragma unroll
        for (int cc = 0; cc < 8; ++cc) { e[cc] = __expf(lrow[cc] - m); den += e[cc]; }
        float rd = __builtin_amdgcn_rcpf(den);
        #pragma unroll
        for (int cc = 0; cc < 8; ++cc) r_arr[p * PXS + cc * 8 + ii] = e[cc] * rd;
    }
    __syncthreads();

    // iter 1
    #pragma unroll
    for (int cc = 0; cc < 2; ++cc) {
        const float4* rp = (const float4*)&r_arr[l15 * PXS + (c0 + cc) * 8];
        float4 r0 = rp[0], r1 = rp[1];
        float pre[4];
        #pragma unroll
        for (int r = 0; r < 4; ++r) {
            float s;
            s  = r0.x * acc[cc][0][r]; s = fmaf(r0.y, acc[cc][1][r], s);
            s  = fmaf(r0.z, acc[cc][2][r], s); s = fmaf(r0.w, acc[cc][3][r], s);
            s  = fmaf(r1.x, acc[cc][4][r], s); s = fmaf(r1.y, acc[cc][5][r], s);
            s  = fmaf(r1.z, acc[cc][6][r], s); s = fmaf(r1.w, acc[cc][7][r], s);
            pre[r] = s + barr[cc][r];
        }
        float s2 = sumquad(pre[0]*pre[0] + pre[1]*pre[1] + pre[2]*pre[2] + pre[3]*pre[3]);
        float scale = s2 * __builtin_amdgcn_rsqf(s2 + EPS) * __builtin_amdgcn_rcpf(1.f + s2);
        #pragma unroll
        for (int r = 0; r < 4; ++r) actv[cc][r] = scale * pre[r];
    }
    #pragma unroll
    for (int cc = 0; cc < 2; ++cc)
        #pragma unroll
        for (int i = 0; i < 8; ++i) {
            float t = acc[cc][i][0]*actv[cc][0] + acc[cc][i][1]*actv[cc][1]
                    + acc[cc][i][2]*actv[cc][2] + acc[cc][i][3]*actv[cc][3];
            t = sumquad(t);
            if (quad == 0) lg_arr[l15 * LSTRIDE + i * 9 + (c0 + cc)] += t;
        }
    __syncthreads();
    if (tid < 128) {
        int p = tid >> 3, ii = tid & 7;
        const float* lrow = &lg_arr[p * LSTRIDE + ii * 9];
        float m = lrow[0];
        #pragma unroll
        for (int cc = 1; cc < 8; ++cc) m = fmaxf(m, lrow[cc]);
        float e[8]; float den = 0.f;
        #pragma unroll
        for (int cc = 0; cc < 8; ++cc) { e[cc] = __expf(lrow[cc] - m); den += e[cc]; }
        float rd = __builtin_amdgcn_rcpf(den);
        #pragma unroll
        for (int cc = 0; cc < 8; ++cc) r_arr[p * PXS + cc * 8 + ii] = e[cc] * rd;
    }
    __syncthreads();

    // iter 2: final activation -> out (per-lane float4: f = quad*4 + 0..3)
    #pragma unroll
    for (int cc = 0; cc < 2; ++cc) {
        const float4* rp = (const float4*)&r_arr[l15 * PXS + (c0 + cc) * 8];
        float4 r0 = rp[0], r1 = rp[1];
        float pre[4];
        #pragma unroll
        for (int r = 0; r < 4; ++r) {
            float s;
            s  = r0.x * acc[cc][0][r]; s = fmaf(r0.y, acc[cc][1][r], s);
            s  = fmaf(r0.z, acc[cc][2][r], s); s = fmaf(r0.w, acc[cc][3][r], s);
            s  = fmaf(r1.x, acc[cc][4][r], s); s = fmaf(r1.y, acc[cc][5][r], s);
            s  = fmaf(r1.z, acc[cc][6][r], s); s = fmaf(r1.w, acc[cc][7][r], s);
            pre[r] = s + barr[cc][r];
        }
        float s2 = sumquad(pre[0]*pre[0] + pre[1]*pre[1] + pre[2]*pre[2] + pre[3]*pre[3]);
        float scale = s2 * __builtin_amdgcn_rsqf(s2 + EPS) * __builtin_amdgcn_rcpf(1.f + s2);
        float4 o4 = { scale*pre[0], scale*pre[1], scale*pre[2], scale*pre[3] };
        int px = pxbase + l15;
        *(float4*)(out + (((b * 32 + h) * 32 + px) << 7) + (c0 + cc) * 16 + quad * 4) = o4;
    }
}

extern "C" void kernel_launch(void* const* d_in, const int* in_sizes, int n_in,
                              void* d_out, int out_size, void* d_ws, size_t ws_size,
                              hipStream_t stream) {
    const float* x    = (const float*)d_in[0];
    const float* wts  = (const float*)d_in[1];
    const float* bias = (const float*)d_in[2];
    float* out        = (float*)d_out;
    _Float16* w16     = (_Float16*)d_ws;

    prep_weights<<<dim3(640), dim3(256), 0, stream>>>(wts, w16);
    capsule_mfma_kernel<<<dim3(2048), dim3(256), 0, stream>>>(x, w16, bias, out);
}